// Round 14
// baseline (359.816 us; speedup 1.0000x reference)
//
#include <hip/hip_runtime.h>
#include <hip/hip_bf16.h>

typedef __hip_bfloat16 bf16;
typedef __attribute__((ext_vector_type(8))) short bf16x8;   // 8 bf16 = 4 VGPRs
typedef __attribute__((ext_vector_type(4))) float f32x4;

constexpr int DD = 128;     // feature dim
constexpr int NAC = 8192;   // actors
constexpr int NND = 65536;  // nodes
constexpr int NEG = 262144; // edges
constexpr int AP = 136;     // Abuf pitch (bf16): 16B-aligned rows; 68 dwords === 4 mod 32 -> 2-way (free)
constexpr float GN_EPS = 1e-5f;

#define DEVINL __device__ __attribute__((always_inline)) static inline

DEVINL float bf2f(short s) {
    return __uint_as_float(((unsigned int)(unsigned short)s) << 16);
}

// ---- async-stage one 64-K half-slice (16 KB) into LDS: 4-wave version ----
DEVINL void stage_half(const bf16* __restrict__ src, bf16* buf, int wid, int lane)
{
    const bf16* g = src + (size_t)(wid * 4) * 512 + lane * 8;
    bf16* l = buf + (wid * 4) * 512;
    #pragma unroll
    for (int i = 0; i < 4; i++) {
        __builtin_amdgcn_global_load_lds(
            (const __attribute__((address_space(1))) void*)(g + i * 512),
            (__attribute__((address_space(3))) void*)(l + i * 512),
            16, 0, 0);
    }
}

// ---- async-stage one 64-K half-slice (16 KB) into LDS: single-wave version ----
DEVINL void stage_h16(const bf16* __restrict__ src, bf16* buf, int lane)
{
    const bf16* g = src + lane * 8;
    #pragma unroll
    for (int i = 0; i < 16; i++) {
        __builtin_amdgcn_global_load_lds(
            (const __attribute__((address_space(1))) void*)(g + i * 512),
            (__attribute__((address_space(3))) void*)(buf + i * 512),
            16, 0, 0);
    }
}

// ---- compute one 64-K half: acc += A[:,kh:kh+64] * Whalf^T ----
DEVINL void compute_half(const bf16* buf, const bf16* Abuf,
                         f32x4 (&acc)[2][8], int eb, int quad, int l16, int lane, int kh)
{
    #pragma unroll
    for (int ks2 = 0; ks2 < 2; ks2++) {
        int kk = kh + ks2 * 32;
        bf16x8 a0 = *(const bf16x8*)(Abuf + (eb + l16) * AP + kk + quad * 8);
        bf16x8 a1 = *(const bf16x8*)(Abuf + (eb + 16 + l16) * AP + kk + quad * 8);
        #pragma unroll
        for (int nt = 0; nt < 8; nt++) {
            bf16x8 b = *(const bf16x8*)(buf + ((ks2 * 8 + nt) * 64 + lane) * 8);
            acc[0][nt] = __builtin_amdgcn_mfma_f32_16x16x32_bf16(a0, b, acc[0][nt], 0, 0, 0);
            acc[1][nt] = __builtin_amdgcn_mfma_f32_16x16x32_bf16(a1, b, acc[1][nt], 0, 0, 0);
        }
    }
}

DEVINL void zero_acc(f32x4 (&acc)[2][8])
{
    #pragma unroll
    for (int i = 0; i < 2; i++)
        #pragma unroll
        for (int j = 0; j < 8; j++)
            acc[i][j] = f32x4{0.f, 0.f, 0.f, 0.f};
}

// ---- in-register GroupNorm(1 group over 128 ch) + ReLU, result -> Abuf (bf16) ----
DEVINL void gn_relu_to_lds(f32x4 (&acc)[2][8], const float* __restrict__ g,
                           const float* __restrict__ b, bf16* Abuf,
                           int eb, int quad, int l16)
{
    float gv[8], bv[8];
    #pragma unroll
    for (int nt = 0; nt < 8; nt++) { gv[nt] = g[nt * 16 + l16]; bv[nt] = b[nt * 16 + l16]; }
    #pragma unroll
    for (int mt = 0; mt < 2; mt++) {
        #pragma unroll
        for (int r = 0; r < 4; r++) {
            float s1 = 0.f, s2 = 0.f;
            #pragma unroll
            for (int nt = 0; nt < 8; nt++) { float v = acc[mt][nt][r]; s1 += v; s2 += v * v; }
            #pragma unroll
            for (int m = 1; m < 16; m <<= 1) { s1 += __shfl_xor(s1, m, 64); s2 += __shfl_xor(s2, m, 64); }
            float mean = s1 * (1.f / 128.f);
            float sc = rsqrtf(s2 * (1.f / 128.f) - mean * mean + GN_EPS);
            int row = eb + mt * 16 + quad * 4 + r;
            #pragma unroll
            for (int nt = 0; nt < 8; nt++) {
                float y = (acc[mt][nt][r] - mean) * sc * gv[nt] + bv[nt];
                Abuf[row * AP + nt * 16 + l16] = __float2bfloat16(fmaxf(y, 0.f));
            }
        }
    }
}

// ---- GroupNorm + ReLU kept in f32 registers (for the edge scatter path) ----
DEVINL void gn_relu_acc(f32x4 (&acc)[2][8], const float* __restrict__ g,
                        const float* __restrict__ b, int l16)
{
    float gv[8], bv[8];
    #pragma unroll
    for (int nt = 0; nt < 8; nt++) { gv[nt] = g[nt * 16 + l16]; bv[nt] = b[nt * 16 + l16]; }
    #pragma unroll
    for (int mt = 0; mt < 2; mt++) {
        #pragma unroll
        for (int r = 0; r < 4; r++) {
            float s1 = 0.f, s2 = 0.f;
            #pragma unroll
            for (int nt = 0; nt < 8; nt++) { float v = acc[mt][nt][r]; s1 += v; s2 += v * v; }
            #pragma unroll
            for (int m = 1; m < 16; m <<= 1) { s1 += __shfl_xor(s1, m, 64); s2 += __shfl_xor(s2, m, 64); }
            float mean = s1 * (1.f / 128.f);
            float sc = rsqrtf(s2 * (1.f / 128.f) - mean * mean + GN_EPS);
            #pragma unroll
            for (int nt = 0; nt < 8; nt++)
                acc[mt][nt][r] = fmaxf((acc[mt][nt][r] - mean) * sc * gv[nt] + bv[nt], 0.f);
        }
    }
}

// pack one output row-position (8 nt channels held by this lane) into a bf16x8
DEVINL bf16x8 pack_row(const f32x4 (&acc)[2][8], int mt, int r)
{
    union { bf16x8 v; bf16 h[8]; } u;
    #pragma unroll
    for (int nt = 0; nt < 8; nt++) u.h[nt] = __float2bfloat16(acc[mt][nt][r]);
    return u.v;
}

// ---- repack all GEMM weight slices fp32 -> bf16 FRAGMENT order; also zero cnt ----
__global__ void repack_w_kernel(const float* __restrict__ d1, const float* __restrict__ qw,
                                const float* __restrict__ c0, const float* __restrict__ c1,
                                const float* __restrict__ ag, const float* __restrict__ li,
                                bf16* __restrict__ Wf, int* __restrict__ cnt)
{
    int g = blockIdx.x * 256 + threadIdx.x;        // 32768 threads
    if (g < 8192) cnt[g] = 0;
    int slice = g >> 11;                            // 16 slices
    int t = g & 2047;
    int i = slice >> 3;                             // att block
    int sid = slice & 7;
    int lane = t & 63, nt = (t >> 6) & 7, ks = t >> 9;
    const float* src; int stride = 128, koff = 0;
    switch (sid) {
        case 0:  src = d1 + i * 16384; break;
        case 1:  src = qw + i * 16384; break;
        case 2:  src = c0 + i * 49152; stride = 384; koff = 0;   break;
        case 3:  src = c0 + i * 49152; stride = 384; koff = 128; break;
        case 4:  src = c0 + i * 49152; stride = 384; koff = 256; break;
        case 5:  src = c1 + i * 16384; break;
        case 6:  src = ag + i * 16384; break;
        default: src = li + i * 16384; break;
    }
    int n = nt * 16 + (lane & 15);
    int k = ks * 32 + (lane >> 4) * 8;
    const float* p = src + (size_t)n * stride + koff + k;
    float4 v0 = *(const float4*)(p);
    float4 v1 = *(const float4*)(p + 4);
    union { bf16x8 v; bf16 h[8]; } u;
    u.h[0] = __float2bfloat16(v0.x); u.h[1] = __float2bfloat16(v0.y);
    u.h[2] = __float2bfloat16(v0.z); u.h[3] = __float2bfloat16(v0.w);
    u.h[4] = __float2bfloat16(v1.x); u.h[5] = __float2bfloat16(v1.y);
    u.h[6] = __float2bfloat16(v1.z); u.h[7] = __float2bfloat16(v1.w);
    *(bf16x8*)(Wf + (size_t)slice * 16384 + (size_t)t * 8) = u.v;
}

// ---- one-time: nodes fp32 -> bf16 with AP pitch (DMA-ready image for nodec) ----
__global__ void nodes_conv_kernel(const float* __restrict__ nodes, bf16* __restrict__ nbp)
{
    int g = blockIdx.x * 256 + threadIdx.x;         // 2M threads, 4 elems each
    int row = g >> 5;
    int c4 = (g & 31) * 4;
    float4 v = *(const float4*)(nodes + (size_t)row * DD + c4);
    bf16* d = nbp + (size_t)row * AP + c4;
    d[0] = __float2bfloat16(v.x); d[1] = __float2bfloat16(v.y);
    d[2] = __float2bfloat16(v.z); d[3] = __float2bfloat16(v.w);
}

// =================== counting sort of edges by hi ===================
__global__ void hist_kernel(const int* __restrict__ hi, int* __restrict__ cnt)
{
    int e = blockIdx.x * blockDim.x + threadIdx.x;
    atomicAdd(&cnt[hi[e]], 1);
}

__global__ void scan_kernel(const int* __restrict__ cnt, int* __restrict__ cur)
{
    __shared__ int part[1024];
    int t = threadIdx.x;
    int local[8]; int s = 0;
    #pragma unroll
    for (int k = 0; k < 8; k++) { local[k] = cnt[t * 8 + k]; s += local[k]; }
    part[t] = s;
    __syncthreads();
    for (int d = 1; d < 1024; d <<= 1) {
        int v = (t >= d) ? part[t - d] : 0;
        __syncthreads();
        part[t] += v;
        __syncthreads();
    }
    int base = t ? part[t - 1] : 0;
    #pragma unroll
    for (int k = 0; k < 8; k++) { cur[t * 8 + k] = base; base += local[k]; }
}

__global__ void scatter_kernel(const int* __restrict__ hi, const int* __restrict__ wi,
                               const float* __restrict__ actor_ctrs, const float* __restrict__ node_ctrs,
                               int* __restrict__ cur,
                               int* __restrict__ hi_s, int* __restrict__ wi_s,
                               float2* __restrict__ dxy_s)
{
    int e = blockIdx.x * blockDim.x + threadIdx.x;
    int h = hi[e], w = wi[e];
    int p = atomicAdd(&cur[h], 1);
    hi_s[p] = h; wi_s[p] = w;
    float2 a2 = ((const float2*)actor_ctrs)[h];
    float2 n2 = ((const float2*)node_ctrs)[w];
    dxy_s[p] = float2{a2.x - n2.x, a2.y - n2.y};
}

// ---- per-node precompute (PER ITERATION, right before edge consumes it):
//      nc = nodes @ Wc^T, fragment-order bf16. Abuf filled by pure DMA from the
//      pre-pitched bf16 nodes image (no VALU convert chain). ----
__global__ __launch_bounds__(256, 3) void nodec_kernel(
    const bf16* __restrict__ nbp, const bf16* __restrict__ c0cf, bf16* __restrict__ nc)
{
    __shared__ __align__(16) bf16 Abuf[128 * AP];   // 34816 B (2176 x 16B chunks)
    __shared__ __align__(16) bf16 Wd[8192];
    int tid = threadIdx.x, wid = tid >> 6, lane = tid & 63, quad = lane >> 4, l16 = lane & 15;
    int eb = wid * 32, r0 = blockIdx.x * 128;
    stage_half(c0cf, Wd, wid, lane);
    {
        const bf16* src = nbp + (size_t)r0 * AP;
        #pragma unroll
        for (int i = 0; i < 9; i++) {
            int idx = i * 256 + tid;
            if (idx < 2176) {
                __builtin_amdgcn_global_load_lds(
                    (const __attribute__((address_space(1))) void*)(src + idx * 8),
                    (__attribute__((address_space(3))) void*)(Abuf + idx * 8),
                    16, 0, 0);
            }
        }
    }
    f32x4 acc[2][8]; zero_acc(acc);
    __syncthreads();                      // Wd h0 + Abuf ready (vmcnt drained)
    compute_half(Wd, Abuf, acc, eb, quad, l16, lane, 0);
    __syncthreads();                      // readers done
    stage_half(c0cf + 8192, Wd, wid, lane);
    __syncthreads();                      // Wd h1 ready
    compute_half(Wd, Abuf, acc, eb, quad, l16, lane, 64);
    #pragma unroll
    for (int mt = 0; mt < 2; mt++)
        #pragma unroll
        for (int r = 0; r < 4; r++) {
            int row = r0 + eb + mt * 16 + quad * 4 + r;
            *(bf16x8*)(nc + (size_t)row * DD + l16 * 8) = pack_row(acc, mt, r);
        }
}

// ---- per-actor precompute, 32-row single-wave blocks (grid=256, all CUs):
//      A_acc = actors @ agt^T (fragment-order f32); zero M_acc rows;
//      q = relu(GN(actors @ query^T)); qc = q @ Wq^T (fragment-order bf16) ----
__global__ __launch_bounds__(64) void prep_kernel(
    const float* __restrict__ actors_in,
    const bf16* __restrict__ agf, const bf16* __restrict__ qwf,
    const float* __restrict__ qg, const float* __restrict__ qb,
    const bf16* __restrict__ c0qf,
    bf16* __restrict__ qc, float* __restrict__ A_acc, float* __restrict__ M_acc)
{
    __shared__ __align__(16) bf16 Abuf[32 * AP];
    __shared__ __align__(16) bf16 Wd[8192];
    int lane = threadIdx.x, quad = lane >> 4, l16 = lane & 15;
    int r0 = blockIdx.x * 32;
    stage_h16(agf, Wd, lane);
    for (int rr = 0; rr < 32; rr++) {
        float2 v = ((const float2*)(actors_in + (size_t)(r0 + rr) * DD))[lane];
        __hip_bfloat162 p; p.x = __float2bfloat16(v.x); p.y = __float2bfloat16(v.y);
        *(__hip_bfloat162*)(Abuf + rr * AP + lane * 2) = p;
    }
    // zero M_acc rows (fused memset; 2 rows per iteration via lane>>5)
    #pragma unroll
    for (int rr = 0; rr < 16; rr++) {
        int row = r0 + rr * 2 + (lane >> 5);
        ((float4*)(M_acc + (size_t)row * DD))[lane & 31] = float4{0.f, 0.f, 0.f, 0.f};
    }
    f32x4 acc[2][8];
    zero_acc(acc);
    __syncthreads();                      // ag h0 ready
    compute_half(Wd, Abuf, acc, 0, quad, l16, lane, 0);
    __syncthreads();
    stage_h16(agf + 8192, Wd, lane);
    __syncthreads();                      // ag h1 ready
    compute_half(Wd, Abuf, acc, 0, quad, l16, lane, 64);
    __syncthreads();                      // Wd free
    stage_h16(qwf, Wd, lane);
    // A_acc in FRAGMENT order f32 (covers qw h0 stage)
    #pragma unroll
    for (int mt = 0; mt < 2; mt++)
        #pragma unroll
        for (int r = 0; r < 4; r++) {
            int row = r0 + mt * 16 + quad * 4 + r;
            float4 w0{acc[mt][0][r], acc[mt][1][r], acc[mt][2][r], acc[mt][3][r]};
            float4 w1{acc[mt][4][r], acc[mt][5][r], acc[mt][6][r], acc[mt][7][r]};
            float4* p = (float4*)(A_acc + (size_t)row * DD + l16 * 8);
            p[0] = w0; p[1] = w1;
        }
    zero_acc(acc);
    __syncthreads();                      // qw h0 ready
    compute_half(Wd, Abuf, acc, 0, quad, l16, lane, 0);
    __syncthreads();
    stage_h16(qwf + 8192, Wd, lane);
    __syncthreads();                      // qw h1 ready
    compute_half(Wd, Abuf, acc, 0, quad, l16, lane, 64);
    __syncthreads();                      // Wd free
    stage_h16(c0qf, Wd, lane);
    gn_relu_to_lds(acc, qg, qb, Abuf, 0, quad, l16);   // covers c0q h0 stage
    zero_acc(acc);
    __syncthreads();                      // c0q h0 ready
    compute_half(Wd, Abuf, acc, 0, quad, l16, lane, 0);
    __syncthreads();
    stage_h16(c0qf + 8192, Wd, lane);
    __syncthreads();                      // c0q h1 ready
    compute_half(Wd, Abuf, acc, 0, quad, l16, lane, 64);
    #pragma unroll
    for (int mt = 0; mt < 2; mt++)
        #pragma unroll
        for (int r = 0; r < 4; r++) {
            int row = r0 + mt * 16 + quad * 4 + r;
            *(bf16x8*)(qc + (size_t)row * DD + l16 * 8) = pack_row(acc, mt, r);
        }
}

// ---- fused edge pipeline on SORTED edges + hierarchical wave-reduced scatter ----
__global__ __launch_bounds__(256, 3) void edge_kernel(
    const int* __restrict__ hi_s, const int* __restrict__ wi_s, const float2* __restrict__ dxy_s,
    const float* __restrict__ d0W, const float* __restrict__ d0b,
    const bf16* __restrict__ d1f, const float* __restrict__ d1g, const float* __restrict__ d1bb,
    const bf16* __restrict__ qc, const bf16* __restrict__ nc,
    const bf16* __restrict__ c0df, const float* __restrict__ c0g, const float* __restrict__ c0bb,
    float* __restrict__ M_acc)
{
    __shared__ __align__(16) bf16 Abuf[128 * AP];   // 34816 B
    __shared__ __align__(16) bf16 Wd[8192];         // 16384 B
    __shared__ float2 dxy[4][32];                   // 1024 B  -> total 52224 B (3 blocks/CU)
    int tid = threadIdx.x, wid = tid >> 6, lane = tid & 63, quad = lane >> 4, l16 = lane & 15;
    int eb = wid * 32, e0 = blockIdx.x * 128 + eb;

    stage_half(d1f, Wd, wid, lane);                 // in flight during stage0

    int hrows[2][4], wrows[2][4];
    #pragma unroll
    for (int mt = 0; mt < 2; mt++)
        #pragma unroll
        for (int r = 0; r < 4; r++) {
            int e = e0 + mt * 16 + quad * 4 + r;
            hrows[mt][r] = hi_s[e];
            wrows[mt][r] = wi_s[e];
        }

    if (lane < 32) dxy[wid][lane] = dxy_s[e0 + lane];
    {
        int ch = lane * 2;
        float w00 = d0W[ch * 2], w01 = d0W[ch * 2 + 1], bb0 = d0b[ch];
        float w10 = d0W[ch * 2 + 2], w11 = d0W[ch * 2 + 3], bb1 = d0b[ch + 1];
        #pragma unroll
        for (int rr = 0; rr < 32; rr++) {
            float2 d = dxy[wid][rr];   // same-wave LDS RAW; compiler inserts lgkmcnt
            float y0 = fmaxf(d.x * w00 + d.y * w01 + bb0, 0.f);
            float y1 = fmaxf(d.x * w10 + d.y * w11 + bb1, 0.f);
            __hip_bfloat162 p; p.x = __float2bfloat16(y0); p.y = __float2bfloat16(y1);
            *(__hip_bfloat162*)(Abuf + (eb + rr) * AP + ch) = p;
        }
    }
    f32x4 acc[2][8];

    // dist1: d = relu(GN(h0 @ dist1^T))
    zero_acc(acc);
    __syncthreads();                                // d1 h0 ready
    compute_half(Wd, Abuf, acc, eb, quad, l16, lane, 0);
    __syncthreads();                                // readers done
    stage_half(d1f + 8192, Wd, wid, lane);
    __syncthreads();                                // d1 h1 ready
    compute_half(Wd, Abuf, acc, eb, quad, l16, lane, 64);
    __syncthreads();                                // Wd free
    stage_half(c0df, Wd, wid, lane);
    gn_relu_to_lds(acc, d1g, d1bb, Abuf, eb, quad, l16);   // VALU covers stage

    // ctx0 acc init = qc[hi] + nc[wi], mt-batched at use (spill-safe: R1/R8 lesson)
    #pragma unroll
    for (int mt = 0; mt < 2; mt++) {
        bf16x8 qv[4], nv[4];
        #pragma unroll
        for (int r = 0; r < 4; r++) {
            qv[r] = *(const bf16x8*)(qc + (size_t)hrows[mt][r] * DD + l16 * 8);
            nv[r] = *(const bf16x8*)(nc + (size_t)wrows[mt][r] * DD + l16 * 8);
        }
        #pragma unroll
        for (int r = 0; r < 4; r++)
            #pragma unroll
            for (int nt = 0; nt < 8; nt++)
                acc[mt][nt][r] = bf2f(qv[r][nt]) + bf2f(nv[r][nt]);
    }
    __syncthreads();                                // c0 h0 ready
    compute_half(Wd, Abuf, acc, eb, quad, l16, lane, 0);
    __syncthreads();
    stage_half(c0df + 8192, Wd, wid, lane);
    __syncthreads();                                // c0 h1 ready
    compute_half(Wd, Abuf, acc, eb, quad, l16, lane, 64);

    // m = relu(GN(ctx0)) in f32 registers, then hierarchical scatter into M_acc[hi]:
    // (a) whole WAVE (32 sorted edges) same actor -> 1 reduce + quad0 atomics;
    // (b) 16-edge mt-group same actor -> per-group reduce + quad0 atomics;
    // (c) fallback: in-lane run reduction.
    gn_relu_acc(acc, c0g, c0bb, l16);
    {
        int href = __shfl(hrows[0][0], 0, 64);
        bool sameAll = true;
        #pragma unroll
        for (int mt = 0; mt < 2; mt++)
            #pragma unroll
            for (int r = 0; r < 4; r++) sameAll = sameAll && (hrows[mt][r] == href);
        if (__all(sameAll)) {
            float s[8];
            #pragma unroll
            for (int nt = 0; nt < 8; nt++) {
                s[nt] = acc[0][nt][0] + acc[0][nt][1] + acc[0][nt][2] + acc[0][nt][3]
                      + acc[1][nt][0] + acc[1][nt][1] + acc[1][nt][2] + acc[1][nt][3];
                s[nt] += __shfl_xor(s[nt], 16, 64);
                s[nt] += __shfl_xor(s[nt], 32, 64);
            }
            if (quad == 0) {
                float* dst = M_acc + (size_t)href * DD + l16;
                #pragma unroll
                for (int nt = 0; nt < 8; nt++) atomicAdd(dst + nt * 16, s[nt]);
            }
        } else {
            #pragma unroll
            for (int mt = 0; mt < 2; mt++) {
                int hrefm = __shfl(hrows[mt][0], 0, 64);
                bool same = (hrows[mt][0] == hrefm) && (hrows[mt][1] == hrefm) &&
                            (hrows[mt][2] == hrefm) && (hrows[mt][3] == hrefm);
                if (__all(same)) {
                    float s[8];
                    #pragma unroll
                    for (int nt = 0; nt < 8; nt++) {
                        s[nt] = acc[mt][nt][0] + acc[mt][nt][1] + acc[mt][nt][2] + acc[mt][nt][3];
                        s[nt] += __shfl_xor(s[nt], 16, 64);
                        s[nt] += __shfl_xor(s[nt], 32, 64);
                    }
                    if (quad == 0) {
                        float* dst = M_acc + (size_t)hrefm * DD + l16;
                        #pragma unroll
                        for (int nt = 0; nt < 8; nt++) atomicAdd(dst + nt * 16, s[nt]);
                    }
                } else {
                    float run[8];
                    int curh = hrows[mt][0];
                    #pragma unroll
                    for (int nt = 0; nt < 8; nt++) run[nt] = acc[mt][nt][0];
                    #pragma unroll
                    for (int r = 1; r < 4; r++) {
                        int hr = hrows[mt][r];
                        if (hr == curh) {
                            #pragma unroll
                            for (int nt = 0; nt < 8; nt++) run[nt] += acc[mt][nt][r];
                        } else {
                            float* dst = M_acc + (size_t)curh * DD + l16;
                            #pragma unroll
                            for (int nt = 0; nt < 8; nt++) atomicAdd(dst + nt * 16, run[nt]);
                            curh = hr;
                            #pragma unroll
                            for (int nt = 0; nt < 8; nt++) run[nt] = acc[mt][nt][r];
                        }
                    }
                    float* dst = M_acc + (size_t)curh * DD + l16;
                    #pragma unroll
                    for (int nt = 0; nt < 8; nt++) atomicAdd(dst + nt * 16, run[nt]);
                }
            }
        }
    }
}

// ---- post, 32-row single-wave blocks (grid=256, all CUs):
//      t = A_acc + M_acc @ c1^T (hi/lo compensated bf16 GEMM);
//      a = relu(GN(t)); out = relu(GN(a @ lin^T) + res) ----
__global__ __launch_bounds__(64) void post_kernel(
    const float* __restrict__ A_acc,   // fragment-order f32 (from prep)
    const float* __restrict__ M_acc,   // channel-order f32 (from edge atomics)
    const bf16* __restrict__ c1f,
    const float* __restrict__ ng, const float* __restrict__ nb,
    const bf16* __restrict__ lif, const float* __restrict__ lg, const float* __restrict__ lb,
    const float* __restrict__ resid, float* __restrict__ outp)
{
    __shared__ __align__(16) bf16 Ahi[32 * AP];
    __shared__ __align__(16) bf16 Alo[32 * AP];
    __shared__ __align__(16) bf16 Wd[8192];
    int lane = threadIdx.x, quad = lane >> 4, l16 = lane & 15;
    int r0 = blockIdx.x * 32;

    stage_h16(c1f, Wd, lane);
    // split M into hi/lo bf16 tiles (compensated: bf16(x) + bf16(x - bf16(x)))
    for (int rr = 0; rr < 32; rr++) {
        float2 x = ((const float2*)(M_acc + (size_t)(r0 + rr) * DD))[lane];
        bf16 h0 = __float2bfloat16(x.x), h1 = __float2bfloat16(x.y);
        float l0 = x.x - __bfloat162float(h0), l1 = x.y - __bfloat162float(h1);
        __hip_bfloat162 ph; ph.x = h0; ph.y = h1;
        __hip_bfloat162 pl; pl.x = __float2bfloat16(l0); pl.y = __float2bfloat16(l1);
        *(__hip_bfloat162*)(Ahi + rr * AP + lane * 2) = ph;
        *(__hip_bfloat162*)(Alo + rr * AP + lane * 2) = pl;
    }
    f32x4 acc[2][8]; zero_acc(acc);
    __syncthreads();                      // c1 h0 ready
    compute_half(Wd, Ahi, acc, 0, quad, l16, lane, 0);
    compute_half(Wd, Alo, acc, 0, quad, l16, lane, 0);
    __syncthreads();
    stage_h16(c1f + 8192, Wd, lane);
    __syncthreads();                      // c1 h1 ready
    compute_half(Wd, Ahi, acc, 0, quad, l16, lane, 64);
    compute_half(Wd, Alo, acc, 0, quad, l16, lane, 64);
    // acc += A_acc (agt output, fragment-order f32, float4 loads)
    #pragma unroll
    for (int mt = 0; mt < 2; mt++)
        #pragma unroll
        for (int r = 0; r < 4; r++) {
            int row = r0 + mt * 16 + quad * 4 + r;
            const float4* p = (const float4*)(A_acc + (size_t)row * DD + l16 * 8);
            float4 v0 = p[0], v1 = p[1];
            acc[mt][0][r] += v0.x; acc[mt][1][r] += v0.y;
            acc[mt][2][r] += v0.z; acc[mt][3][r] += v0.w;
            acc[mt][4][r] += v1.x; acc[mt][5][r] += v1.y;
            acc[mt][6][r] += v1.z; acc[mt][7][r] += v1.w;
        }
    __syncthreads();                      // Wd free
    stage_h16(lif, Wd, lane);
    gn_relu_to_lds(acc, ng, nb, Ahi, 0, quad, l16);   // a -> Ahi; covers lin h0 stage
    f32x4 acc2[2][8]; zero_acc(acc2);
    __syncthreads();                      // lin h0 ready
    compute_half(Wd, Ahi, acc2, 0, quad, l16, lane, 0);
    __syncthreads();
    stage_h16(lif + 8192, Wd, lane);
    __syncthreads();                      // lin h1 ready
    compute_half(Wd, Ahi, acc2, 0, quad, l16, lane, 64);

    float gv[8], bv[8];
    #pragma unroll
    for (int nt = 0; nt < 8; nt++) { gv[nt] = lg[nt * 16 + l16]; bv[nt] = lb[nt * 16 + l16]; }
    #pragma unroll
    for (int mt = 0; mt < 2; mt++)
        #pragma unroll
        for (int r = 0; r < 4; r++) {
            float s1 = 0.f, s2 = 0.f;
            #pragma unroll
            for (int nt = 0; nt < 8; nt++) { float v = acc2[mt][nt][r]; s1 += v; s2 += v * v; }
            #pragma unroll
            for (int m = 1; m < 16; m <<= 1) { s1 += __shfl_xor(s1, m, 64); s2 += __shfl_xor(s2, m, 64); }
            float mean = s1 * (1.f / 128.f);
            float sc = rsqrtf(s2 * (1.f / 128.f) - mean * mean + GN_EPS);
            int row = r0 + mt * 16 + quad * 4 + r;
            #pragma unroll
            for (int nt = 0; nt < 8; nt++) {
                float y = (acc2[mt][nt][r] - mean) * sc * gv[nt] + bv[nt];  // act=False before residual
                size_t o = (size_t)row * DD + nt * 16 + l16;
                outp[o] = fmaxf(y + resid[o], 0.f);
            }
        }
}

extern "C" void kernel_launch(void* const* d_in, const int* in_sizes, int n_in,
                              void* d_out, int out_size, void* d_ws, size_t ws_size,
                              hipStream_t stream)
{
    const float* actors     = (const float*)d_in[0];
    const float* nodes      = (const float*)d_in[1];
    const float* actor_ctrs = (const float*)d_in[2];
    const float* node_ctrs  = (const float*)d_in[3];
    const int*   hi         = (const int*)d_in[4];
    const int*   wi         = (const int*)d_in[5];
    const float* dist0_W    = (const float*)d_in[6];
    const float* dist0_b    = (const float*)d_in[7];
    const float* dist1_W    = (const float*)d_in[8];
    const float* dist1_g    = (const float*)d_in[9];
    const float* dist1_b    = (const float*)d_in[10];
    const float* query_W    = (const float*)d_in[11];
    const float* query_g    = (const float*)d_in[12];
    const float* query_b    = (const float*)d_in[13];
    const float* ctx0_W     = (const float*)d_in[14];
    const float* ctx0_g     = (const float*)d_in[15];
    const float* ctx0_b     = (const float*)d_in[16];
    const float* ctx1_W     = (const float*)d_in[17];
    const float* agt_W      = (const float*)d_in[18];
    const float* norm_g     = (const float*)d_in[19];
    const float* norm_b     = (const float*)d_in[20];
    const float* lin_W      = (const float*)d_in[21];
    const float* lin_g      = (const float*)d_in[22];
    const float* lin_b      = (const float*)d_in[23];

    // workspace layout (~52.5 MB)
    char* ws = (char*)d_ws;
    size_t off = 0;
    bf16*  Wf         = (bf16*)(ws + off);  off += 524288;      // 16 slices x 32 KB, fragment order
    float* A_acc      = (float*)(ws + off); off += 4194304;     // agt output, fragment-order f32
    float* M_acc      = (float*)(ws + off); off += 4194304;     // per-actor sum of m, ch-order f32
    float* actors_mid = (float*)(ws + off); off += 4194304;     // 4 MB
    bf16*  qc_bf      = (bf16*)(ws + off);  off += 2097152;     // 2 MB
    bf16*  nc_bf      = (bf16*)(ws + off);  off += 16777216;    // 16 MB
    bf16*  nodes_bfp  = (bf16*)(ws + off);  off += 17825792;    // 65536 x AP bf16 (DMA image)
    int*   cnt        = (int*)(ws + off);   off += 32768;       // 8192 ints
    int*   cur        = (int*)(ws + off);   off += 32768;       // 8192 ints
    int*   hi_s       = (int*)(ws + off);   off += 1048576;     // E ints
    int*   wi_s       = (int*)(ws + off);   off += 1048576;     // E ints
    float2* dxy_s     = (float2*)(ws + off); off += 2097152;    // E float2

    repack_w_kernel<<<128, 256, 0, stream>>>(dist1_W, query_W, ctx0_W, ctx1_W, agt_W, lin_W,
                                             Wf, cnt);
    nodes_conv_kernel<<<NND * 32 / 256, 256, 0, stream>>>(nodes, nodes_bfp);

    // counting sort by hi (shared by both Att blocks)
    hist_kernel<<<NEG / 256, 256, 0, stream>>>(hi, cnt);
    scan_kernel<<<1, 1024, 0, stream>>>(cnt, cur);
    scatter_kernel<<<NEG / 256, 256, 0, stream>>>(hi, wi, actor_ctrs, node_ctrs,
                                                  cur, hi_s, wi_s, dxy_s);

    for (int i = 0; i < 2; i++) {
        const bf16* d1f  = Wf + (size_t)(i * 8 + 0) * 16384;
        const bf16* qwf  = Wf + (size_t)(i * 8 + 1) * 16384;
        const bf16* c0df = Wf + (size_t)(i * 8 + 2) * 16384;
        const bf16* c0qf = Wf + (size_t)(i * 8 + 3) * 16384;
        const bf16* c0cf = Wf + (size_t)(i * 8 + 4) * 16384;
        const bf16* c1f  = Wf + (size_t)(i * 8 + 5) * 16384;
        const bf16* agf  = Wf + (size_t)(i * 8 + 6) * 16384;
        const bf16* lif  = Wf + (size_t)(i * 8 + 7) * 16384;
        const float* curp = i ? actors_mid : actors;
        float* nxt = i ? (float*)d_out : actors_mid;

        nodec_kernel<<<NND / 128, 256, 0, stream>>>(nodes_bfp, c0cf, nc_bf);
        prep_kernel<<<NAC / 32, 64, 0, stream>>>(curp, agf, qwf,
            query_g + i * 128, query_b + i * 128, c0qf, qc_bf, A_acc, M_acc);
        edge_kernel<<<NEG / 128, 256, 0, stream>>>(hi_s, wi_s, dxy_s,
            dist0_W + i * 256, dist0_b + i * 128,
            d1f, dist1_g + i * 128, dist1_b + i * 128,
            qc_bf, nc_bf, c0df, ctx0_g + i * 128, ctx0_b + i * 128, M_acc);
        post_kernel<<<NAC / 32, 64, 0, stream>>>(A_acc, M_acc, c1f,
            norm_g + i * 128, norm_b + i * 128,
            lif, lin_g + i * 128, lin_b + i * 128, curp, nxt);
    }
}

// Round 15
// 345.594 us; speedup vs baseline: 1.0412x; 1.0412x over previous
//
#include <hip/hip_runtime.h>
#include <hip/hip_bf16.h>

typedef __hip_bfloat16 bf16;
typedef __attribute__((ext_vector_type(8))) short bf16x8;   // 8 bf16 = 4 VGPRs
typedef __attribute__((ext_vector_type(4))) float f32x4;

constexpr int DD = 128;     // feature dim
constexpr int NAC = 8192;   // actors
constexpr int NND = 65536;  // nodes
constexpr int NEG = 262144; // edges
constexpr int AP = 136;     // Abuf pitch (bf16): 16B-aligned rows; 68 dwords === 4 mod 32 -> 2-way (free)
constexpr float GN_EPS = 1e-5f;

#define DEVINL __device__ __attribute__((always_inline)) static inline

DEVINL float bf2f(short s) {
    return __uint_as_float(((unsigned int)(unsigned short)s) << 16);
}

// ---- async-stage one 64-K half-slice (16 KB) into LDS: 4-wave version ----
DEVINL void stage_half(const bf16* __restrict__ src, bf16* buf, int wid, int lane)
{
    const bf16* g = src + (size_t)(wid * 4) * 512 + lane * 8;
    bf16* l = buf + (wid * 4) * 512;
    #pragma unroll
    for (int i = 0; i < 4; i++) {
        __builtin_amdgcn_global_load_lds(
            (const __attribute__((address_space(1))) void*)(g + i * 512),
            (__attribute__((address_space(3))) void*)(l + i * 512),
            16, 0, 0);
    }
}

// ---- async-stage one 64-K half-slice (16 KB) into LDS: single-wave version ----
DEVINL void stage_h16(const bf16* __restrict__ src, bf16* buf, int lane)
{
    const bf16* g = src + lane * 8;
    #pragma unroll
    for (int i = 0; i < 16; i++) {
        __builtin_amdgcn_global_load_lds(
            (const __attribute__((address_space(1))) void*)(g + i * 512),
            (__attribute__((address_space(3))) void*)(buf + i * 512),
            16, 0, 0);
    }
}

// ---- compute one 64-K half: acc += A[:,kh:kh+64] * Whalf^T ----
DEVINL void compute_half(const bf16* buf, const bf16* Abuf,
                         f32x4 (&acc)[2][8], int eb, int quad, int l16, int lane, int kh)
{
    #pragma unroll
    for (int ks2 = 0; ks2 < 2; ks2++) {
        int kk = kh + ks2 * 32;
        bf16x8 a0 = *(const bf16x8*)(Abuf + (eb + l16) * AP + kk + quad * 8);
        bf16x8 a1 = *(const bf16x8*)(Abuf + (eb + 16 + l16) * AP + kk + quad * 8);
        #pragma unroll
        for (int nt = 0; nt < 8; nt++) {
            bf16x8 b = *(const bf16x8*)(buf + ((ks2 * 8 + nt) * 64 + lane) * 8);
            acc[0][nt] = __builtin_amdgcn_mfma_f32_16x16x32_bf16(a0, b, acc[0][nt], 0, 0, 0);
            acc[1][nt] = __builtin_amdgcn_mfma_f32_16x16x32_bf16(a1, b, acc[1][nt], 0, 0, 0);
        }
    }
}

DEVINL void zero_acc(f32x4 (&acc)[2][8])
{
    #pragma unroll
    for (int i = 0; i < 2; i++)
        #pragma unroll
        for (int j = 0; j < 8; j++)
            acc[i][j] = f32x4{0.f, 0.f, 0.f, 0.f};
}

// ---- in-register GroupNorm(1 group over 128 ch) + ReLU, result -> Abuf (bf16) ----
DEVINL void gn_relu_to_lds(f32x4 (&acc)[2][8], const float* __restrict__ g,
                           const float* __restrict__ b, bf16* Abuf,
                           int eb, int quad, int l16)
{
    float gv[8], bv[8];
    #pragma unroll
    for (int nt = 0; nt < 8; nt++) { gv[nt] = g[nt * 16 + l16]; bv[nt] = b[nt * 16 + l16]; }
    #pragma unroll
    for (int mt = 0; mt < 2; mt++) {
        #pragma unroll
        for (int r = 0; r < 4; r++) {
            float s1 = 0.f, s2 = 0.f;
            #pragma unroll
            for (int nt = 0; nt < 8; nt++) { float v = acc[mt][nt][r]; s1 += v; s2 += v * v; }
            #pragma unroll
            for (int m = 1; m < 16; m <<= 1) { s1 += __shfl_xor(s1, m, 64); s2 += __shfl_xor(s2, m, 64); }
            float mean = s1 * (1.f / 128.f);
            float sc = rsqrtf(s2 * (1.f / 128.f) - mean * mean + GN_EPS);
            int row = eb + mt * 16 + quad * 4 + r;
            #pragma unroll
            for (int nt = 0; nt < 8; nt++) {
                float y = (acc[mt][nt][r] - mean) * sc * gv[nt] + bv[nt];
                Abuf[row * AP + nt * 16 + l16] = __float2bfloat16(fmaxf(y, 0.f));
            }
        }
    }
}

// ---- GroupNorm + ReLU kept in f32 registers (for the edge scatter path) ----
DEVINL void gn_relu_acc(f32x4 (&acc)[2][8], const float* __restrict__ g,
                        const float* __restrict__ b, int l16)
{
    float gv[8], bv[8];
    #pragma unroll
    for (int nt = 0; nt < 8; nt++) { gv[nt] = g[nt * 16 + l16]; bv[nt] = b[nt * 16 + l16]; }
    #pragma unroll
    for (int mt = 0; mt < 2; mt++) {
        #pragma unroll
        for (int r = 0; r < 4; r++) {
            float s1 = 0.f, s2 = 0.f;
            #pragma unroll
            for (int nt = 0; nt < 8; nt++) { float v = acc[mt][nt][r]; s1 += v; s2 += v * v; }
            #pragma unroll
            for (int m = 1; m < 16; m <<= 1) { s1 += __shfl_xor(s1, m, 64); s2 += __shfl_xor(s2, m, 64); }
            float mean = s1 * (1.f / 128.f);
            float sc = rsqrtf(s2 * (1.f / 128.f) - mean * mean + GN_EPS);
            #pragma unroll
            for (int nt = 0; nt < 8; nt++)
                acc[mt][nt][r] = fmaxf((acc[mt][nt][r] - mean) * sc * gv[nt] + bv[nt], 0.f);
        }
    }
}

// pack one output row-position (8 nt channels held by this lane) into a bf16x8
DEVINL bf16x8 pack_row(const f32x4 (&acc)[2][8], int mt, int r)
{
    union { bf16x8 v; bf16 h[8]; } u;
    #pragma unroll
    for (int nt = 0; nt < 8; nt++) u.h[nt] = __float2bfloat16(acc[mt][nt][r]);
    return u.v;
}

// ---- repack all GEMM weight slices fp32 -> bf16 FRAGMENT order; also zero cnt ----
__global__ void repack_w_kernel(const float* __restrict__ d1, const float* __restrict__ qw,
                                const float* __restrict__ c0, const float* __restrict__ c1,
                                const float* __restrict__ ag, const float* __restrict__ li,
                                bf16* __restrict__ Wf, int* __restrict__ cnt)
{
    int g = blockIdx.x * 256 + threadIdx.x;        // 32768 threads
    if (g < 8192) cnt[g] = 0;
    int slice = g >> 11;                            // 16 slices
    int t = g & 2047;
    int i = slice >> 3;                             // att block
    int sid = slice & 7;
    int lane = t & 63, nt = (t >> 6) & 7, ks = t >> 9;
    const float* src; int stride = 128, koff = 0;
    switch (sid) {
        case 0:  src = d1 + i * 16384; break;
        case 1:  src = qw + i * 16384; break;
        case 2:  src = c0 + i * 49152; stride = 384; koff = 0;   break;
        case 3:  src = c0 + i * 49152; stride = 384; koff = 128; break;
        case 4:  src = c0 + i * 49152; stride = 384; koff = 256; break;
        case 5:  src = c1 + i * 16384; break;
        case 6:  src = ag + i * 16384; break;
        default: src = li + i * 16384; break;
    }
    int n = nt * 16 + (lane & 15);
    int k = ks * 32 + (lane >> 4) * 8;
    const float* p = src + (size_t)n * stride + koff + k;
    float4 v0 = *(const float4*)(p);
    float4 v1 = *(const float4*)(p + 4);
    union { bf16x8 v; bf16 h[8]; } u;
    u.h[0] = __float2bfloat16(v0.x); u.h[1] = __float2bfloat16(v0.y);
    u.h[2] = __float2bfloat16(v0.z); u.h[3] = __float2bfloat16(v0.w);
    u.h[4] = __float2bfloat16(v1.x); u.h[5] = __float2bfloat16(v1.y);
    u.h[6] = __float2bfloat16(v1.z); u.h[7] = __float2bfloat16(v1.w);
    *(bf16x8*)(Wf + (size_t)slice * 16384 + (size_t)t * 8) = u.v;
}

// =================== counting sort of edges by hi ===================
__global__ void hist_kernel(const int* __restrict__ hi, int* __restrict__ cnt)
{
    int e = blockIdx.x * blockDim.x + threadIdx.x;
    atomicAdd(&cnt[hi[e]], 1);
}

__global__ void scan_kernel(const int* __restrict__ cnt, int* __restrict__ cur)
{
    __shared__ int part[1024];
    int t = threadIdx.x;
    int local[8]; int s = 0;
    #pragma unroll
    for (int k = 0; k < 8; k++) { local[k] = cnt[t * 8 + k]; s += local[k]; }
    part[t] = s;
    __syncthreads();
    for (int d = 1; d < 1024; d <<= 1) {
        int v = (t >= d) ? part[t - d] : 0;
        __syncthreads();
        part[t] += v;
        __syncthreads();
    }
    int base = t ? part[t - 1] : 0;
    #pragma unroll
    for (int k = 0; k < 8; k++) { cur[t * 8 + k] = base; base += local[k]; }
}

__global__ void scatter_kernel(const int* __restrict__ hi, const int* __restrict__ wi,
                               const float* __restrict__ actor_ctrs, const float* __restrict__ node_ctrs,
                               int* __restrict__ cur,
                               int* __restrict__ hi_s, int* __restrict__ wi_s,
                               float2* __restrict__ dxy_s)
{
    int e = blockIdx.x * blockDim.x + threadIdx.x;
    int h = hi[e], w = wi[e];
    int p = atomicAdd(&cur[h], 1);
    hi_s[p] = h; wi_s[p] = w;
    float2 a2 = ((const float2*)actor_ctrs)[h];
    float2 n2 = ((const float2*)node_ctrs)[w];
    dxy_s[p] = float2{a2.x - n2.x, a2.y - n2.y};
}

// ---- FUSED per-iteration precompute: blocks 0..511 = nodec (nc = nodes @ Wc^T),
//      blocks 512..575 = prep (A_acc, M_acc zero, qc). Both only feed edge, so
//      horizontal fusion is legal; prep's latency hides under nodec's. ----
__global__ __launch_bounds__(256, 3) void nodecprep_kernel(
    const float* __restrict__ nodes, const bf16* __restrict__ c0cf, bf16* __restrict__ nc,
    const float* __restrict__ actors_in,
    const bf16* __restrict__ agf, const bf16* __restrict__ qwf,
    const float* __restrict__ qg, const float* __restrict__ qb,
    const bf16* __restrict__ c0qf,
    bf16* __restrict__ qc, float* __restrict__ A_acc, float* __restrict__ M_acc)
{
    __shared__ __align__(16) bf16 Abuf[128 * AP];
    __shared__ __align__(16) bf16 Wd[8192];
    int tid = threadIdx.x, wid = tid >> 6, lane = tid & 63, quad = lane >> 4, l16 = lane & 15;
    int eb = wid * 32;

    if (blockIdx.x < 512) {
        // ---------------- nodec body ----------------
        int r0 = blockIdx.x * 128;
        stage_half(c0cf, Wd, wid, lane);
        for (int rr = 0; rr < 32; rr++) {
            int row = r0 + eb + rr;
            float2 v = ((const float2*)(nodes + (size_t)row * DD))[lane];
            __hip_bfloat162 p; p.x = __float2bfloat16(v.x); p.y = __float2bfloat16(v.y);
            *(__hip_bfloat162*)(Abuf + (eb + rr) * AP + lane * 2) = p;
        }
        f32x4 acc[2][8]; zero_acc(acc);
        __syncthreads();                      // Wd h0 ready
        compute_half(Wd, Abuf, acc, eb, quad, l16, lane, 0);
        __syncthreads();                      // readers done
        stage_half(c0cf + 8192, Wd, wid, lane);
        __syncthreads();                      // Wd h1 ready
        compute_half(Wd, Abuf, acc, eb, quad, l16, lane, 64);
        #pragma unroll
        for (int mt = 0; mt < 2; mt++)
            #pragma unroll
            for (int r = 0; r < 4; r++) {
                int row = r0 + eb + mt * 16 + quad * 4 + r;
                *(bf16x8*)(nc + (size_t)row * DD + l16 * 8) = pack_row(acc, mt, r);
            }
    } else {
        // ---------------- prep body (4-wave, 128 rows/block) ----------------
        int r0 = (blockIdx.x - 512) * 128;
        stage_half(agf, Wd, wid, lane);
        for (int rr = 0; rr < 32; rr++) {
            int row = r0 + eb + rr;
            float2 v = ((const float2*)(actors_in + (size_t)row * DD))[lane];
            __hip_bfloat162 p; p.x = __float2bfloat16(v.x); p.y = __float2bfloat16(v.y);
            *(__hip_bfloat162*)(Abuf + (eb + rr) * AP + lane * 2) = p;
        }
        // zero this block's 128 M_acc rows (4096 float4 over 256 threads)
        #pragma unroll
        for (int j = 0; j < 16; j++)
            ((float4*)(M_acc + (size_t)r0 * DD))[j * 256 + tid] = float4{0.f, 0.f, 0.f, 0.f};
        f32x4 acc[2][8];
        zero_acc(acc);
        __syncthreads();                      // ag h0 ready
        compute_half(Wd, Abuf, acc, eb, quad, l16, lane, 0);
        __syncthreads();
        stage_half(agf + 8192, Wd, wid, lane);
        __syncthreads();                      // ag h1 ready
        compute_half(Wd, Abuf, acc, eb, quad, l16, lane, 64);
        __syncthreads();                      // Wd free
        stage_half(qwf, Wd, wid, lane);
        // A_acc in FRAGMENT order f32 (covers qw h0 stage)
        #pragma unroll
        for (int mt = 0; mt < 2; mt++)
            #pragma unroll
            for (int r = 0; r < 4; r++) {
                int row = r0 + eb + mt * 16 + quad * 4 + r;
                float4 w0{acc[mt][0][r], acc[mt][1][r], acc[mt][2][r], acc[mt][3][r]};
                float4 w1{acc[mt][4][r], acc[mt][5][r], acc[mt][6][r], acc[mt][7][r]};
                float4* p = (float4*)(A_acc + (size_t)row * DD + l16 * 8);
                p[0] = w0; p[1] = w1;
            }
        zero_acc(acc);
        __syncthreads();                      // qw h0 ready
        compute_half(Wd, Abuf, acc, eb, quad, l16, lane, 0);
        __syncthreads();
        stage_half(qwf + 8192, Wd, wid, lane);
        __syncthreads();                      // qw h1 ready
        compute_half(Wd, Abuf, acc, eb, quad, l16, lane, 64);
        __syncthreads();                      // Wd free
        stage_half(c0qf, Wd, wid, lane);
        gn_relu_to_lds(acc, qg, qb, Abuf, eb, quad, l16);   // covers c0q h0 stage
        zero_acc(acc);
        __syncthreads();                      // c0q h0 ready
        compute_half(Wd, Abuf, acc, eb, quad, l16, lane, 0);
        __syncthreads();
        stage_half(c0qf + 8192, Wd, wid, lane);
        __syncthreads();                      // c0q h1 ready
        compute_half(Wd, Abuf, acc, eb, quad, l16, lane, 64);
        #pragma unroll
        for (int mt = 0; mt < 2; mt++)
            #pragma unroll
            for (int r = 0; r < 4; r++) {
                int row = r0 + eb + mt * 16 + quad * 4 + r;
                *(bf16x8*)(qc + (size_t)row * DD + l16 * 8) = pack_row(acc, mt, r);
            }
    }
}

// ---- fused edge pipeline on SORTED edges (R13 structure, unchanged) ----
__global__ __launch_bounds__(256, 3) void edge_kernel(
    const int* __restrict__ hi_s, const int* __restrict__ wi_s, const float2* __restrict__ dxy_s,
    const float* __restrict__ d0W, const float* __restrict__ d0b,
    const bf16* __restrict__ d1f, const float* __restrict__ d1g, const float* __restrict__ d1bb,
    const bf16* __restrict__ qc, const bf16* __restrict__ nc,
    const bf16* __restrict__ c0df, const float* __restrict__ c0g, const float* __restrict__ c0bb,
    float* __restrict__ M_acc)
{
    __shared__ __align__(16) bf16 Abuf[128 * AP];   // 34816 B
    __shared__ __align__(16) bf16 Wd[8192];         // 16384 B
    __shared__ float2 dxy[4][32];                   // 1024 B  -> total 52224 B (3 blocks/CU)
    int tid = threadIdx.x, wid = tid >> 6, lane = tid & 63, quad = lane >> 4, l16 = lane & 15;
    int eb = wid * 32, e0 = blockIdx.x * 128 + eb;

    stage_half(d1f, Wd, wid, lane);                 // in flight during stage0

    int hrows[2][4], wrows[2][4];
    #pragma unroll
    for (int mt = 0; mt < 2; mt++)
        #pragma unroll
        for (int r = 0; r < 4; r++) {
            int e = e0 + mt * 16 + quad * 4 + r;
            hrows[mt][r] = hi_s[e];
            wrows[mt][r] = wi_s[e];
        }

    if (lane < 32) dxy[wid][lane] = dxy_s[e0 + lane];
    {
        int ch = lane * 2;
        float w00 = d0W[ch * 2], w01 = d0W[ch * 2 + 1], bb0 = d0b[ch];
        float w10 = d0W[ch * 2 + 2], w11 = d0W[ch * 2 + 3], bb1 = d0b[ch + 1];
        #pragma unroll
        for (int rr = 0; rr < 32; rr++) {
            float2 d = dxy[wid][rr];   // same-wave LDS RAW; compiler inserts lgkmcnt
            float y0 = fmaxf(d.x * w00 + d.y * w01 + bb0, 0.f);
            float y1 = fmaxf(d.x * w10 + d.y * w11 + bb1, 0.f);
            __hip_bfloat162 p; p.x = __float2bfloat16(y0); p.y = __float2bfloat16(y1);
            *(__hip_bfloat162*)(Abuf + (eb + rr) * AP + ch) = p;
        }
    }
    f32x4 acc[2][8];

    // dist1: d = relu(GN(h0 @ dist1^T))
    zero_acc(acc);
    __syncthreads();                                // d1 h0 ready
    compute_half(Wd, Abuf, acc, eb, quad, l16, lane, 0);
    __syncthreads();                                // readers done
    stage_half(d1f + 8192, Wd, wid, lane);
    __syncthreads();                                // d1 h1 ready
    compute_half(Wd, Abuf, acc, eb, quad, l16, lane, 64);
    __syncthreads();                                // Wd free
    stage_half(c0df, Wd, wid, lane);
    gn_relu_to_lds(acc, d1g, d1bb, Abuf, eb, quad, l16);   // VALU covers stage

    // ctx0 acc init = qc[hi] + nc[wi], mt-batched at use (spill-safe: R1/R8 lesson)
    #pragma unroll
    for (int mt = 0; mt < 2; mt++) {
        bf16x8 qv[4], nv[4];
        #pragma unroll
        for (int r = 0; r < 4; r++) {
            qv[r] = *(const bf16x8*)(qc + (size_t)hrows[mt][r] * DD + l16 * 8);
            nv[r] = *(const bf16x8*)(nc + (size_t)wrows[mt][r] * DD + l16 * 8);
        }
        #pragma unroll
        for (int r = 0; r < 4; r++)
            #pragma unroll
            for (int nt = 0; nt < 8; nt++)
                acc[mt][nt][r] = bf2f(qv[r][nt]) + bf2f(nv[r][nt]);
    }
    __syncthreads();                                // c0 h0 ready
    compute_half(Wd, Abuf, acc, eb, quad, l16, lane, 0);
    __syncthreads();
    stage_half(c0df + 8192, Wd, wid, lane);
    __syncthreads();                                // c0 h1 ready
    compute_half(Wd, Abuf, acc, eb, quad, l16, lane, 64);

    // m = relu(GN(ctx0)) in f32 registers, then scatter into M_acc[hi].
    // Fast path: 16-edge mt-group shares one actor (sorted, mean degree 32)
    // -> cross-quad tree reduce, quad-0 atomics only.
    gn_relu_acc(acc, c0g, c0bb, l16);
    #pragma unroll
    for (int mt = 0; mt < 2; mt++) {
        int h0 = hrows[mt][0];
        int href = __shfl(h0, 0, 64);
        bool same = (hrows[mt][0] == href) && (hrows[mt][1] == href) &&
                    (hrows[mt][2] == href) && (hrows[mt][3] == href);
        if (__all(same)) {
            float s[8];
            #pragma unroll
            for (int nt = 0; nt < 8; nt++) {
                s[nt] = acc[mt][nt][0] + acc[mt][nt][1] + acc[mt][nt][2] + acc[mt][nt][3];
                s[nt] += __shfl_xor(s[nt], 16, 64);
                s[nt] += __shfl_xor(s[nt], 32, 64);
            }
            if (quad == 0) {
                float* dst = M_acc + (size_t)href * DD + l16;
                #pragma unroll
                for (int nt = 0; nt < 8; nt++) atomicAdd(dst + nt * 16, s[nt]);
            }
        } else {
            float run[8];
            int curh = hrows[mt][0];
            #pragma unroll
            for (int nt = 0; nt < 8; nt++) run[nt] = acc[mt][nt][0];
            #pragma unroll
            for (int r = 1; r < 4; r++) {
                int hr = hrows[mt][r];
                if (hr == curh) {
                    #pragma unroll
                    for (int nt = 0; nt < 8; nt++) run[nt] += acc[mt][nt][r];
                } else {
                    float* dst = M_acc + (size_t)curh * DD + l16;
                    #pragma unroll
                    for (int nt = 0; nt < 8; nt++) atomicAdd(dst + nt * 16, run[nt]);
                    curh = hr;
                    #pragma unroll
                    for (int nt = 0; nt < 8; nt++) run[nt] = acc[mt][nt][r];
                }
            }
            float* dst = M_acc + (size_t)curh * DD + l16;
            #pragma unroll
            for (int nt = 0; nt < 8; nt++) atomicAdd(dst + nt * 16, run[nt]);
        }
    }
}

// ---- post, 32-row single-wave blocks (grid=256, all CUs):
//      t = A_acc + M_acc @ c1^T (hi/lo compensated bf16 GEMM);
//      a = relu(GN(t)); out = relu(GN(a @ lin^T) + res) ----
__global__ __launch_bounds__(64) void post_kernel(
    const float* __restrict__ A_acc,   // fragment-order f32 (from prep)
    const float* __restrict__ M_acc,   // channel-order f32 (from edge atomics)
    const bf16* __restrict__ c1f,
    const float* __restrict__ ng, const float* __restrict__ nb,
    const bf16* __restrict__ lif, const float* __restrict__ lg, const float* __restrict__ lb,
    const float* __restrict__ resid, float* __restrict__ outp)
{
    __shared__ __align__(16) bf16 Ahi[32 * AP];
    __shared__ __align__(16) bf16 Alo[32 * AP];
    __shared__ __align__(16) bf16 Wd[8192];
    int lane = threadIdx.x, quad = lane >> 4, l16 = lane & 15;
    int r0 = blockIdx.x * 32;

    stage_h16(c1f, Wd, lane);
    // split M into hi/lo bf16 tiles (compensated: bf16(x) + bf16(x - bf16(x)))
    for (int rr = 0; rr < 32; rr++) {
        float2 x = ((const float2*)(M_acc + (size_t)(r0 + rr) * DD))[lane];
        bf16 h0 = __float2bfloat16(x.x), h1 = __float2bfloat16(x.y);
        float l0 = x.x - __bfloat162float(h0), l1 = x.y - __bfloat162float(h1);
        __hip_bfloat162 ph; ph.x = h0; ph.y = h1;
        __hip_bfloat162 pl; pl.x = __float2bfloat16(l0); pl.y = __float2bfloat16(l1);
        *(__hip_bfloat162*)(Ahi + rr * AP + lane * 2) = ph;
        *(__hip_bfloat162*)(Alo + rr * AP + lane * 2) = pl;
    }
    f32x4 acc[2][8]; zero_acc(acc);
    __syncthreads();                      // c1 h0 ready
    compute_half(Wd, Ahi, acc, 0, quad, l16, lane, 0);
    compute_half(Wd, Alo, acc, 0, quad, l16, lane, 0);
    __syncthreads();
    stage_h16(c1f + 8192, Wd, lane);
    __syncthreads();                      // c1 h1 ready
    compute_half(Wd, Ahi, acc, 0, quad, l16, lane, 64);
    compute_half(Wd, Alo, acc, 0, quad, l16, lane, 64);
    // acc += A_acc (agt output, fragment-order f32, float4 loads)
    #pragma unroll
    for (int mt = 0; mt < 2; mt++)
        #pragma unroll
        for (int r = 0; r < 4; r++) {
            int row = r0 + mt * 16 + quad * 4 + r;
            const float4* p = (const float4*)(A_acc + (size_t)row * DD + l16 * 8);
            float4 v0 = p[0], v1 = p[1];
            acc[mt][0][r] += v0.x; acc[mt][1][r] += v0.y;
            acc[mt][2][r] += v0.z; acc[mt][3][r] += v0.w;
            acc[mt][4][r] += v1.x; acc[mt][5][r] += v1.y;
            acc[mt][6][r] += v1.z; acc[mt][7][r] += v1.w;
        }
    __syncthreads();                      // Wd free
    stage_h16(lif, Wd, lane);
    gn_relu_to_lds(acc, ng, nb, Ahi, 0, quad, l16);   // a -> Ahi; covers lin h0 stage
    f32x4 acc2[2][8]; zero_acc(acc2);
    __syncthreads();                      // lin h0 ready
    compute_half(Wd, Ahi, acc2, 0, quad, l16, lane, 0);
    __syncthreads();
    stage_h16(lif + 8192, Wd, lane);
    __syncthreads();                      // lin h1 ready
    compute_half(Wd, Ahi, acc2, 0, quad, l16, lane, 64);

    float gv[8], bv[8];
    #pragma unroll
    for (int nt = 0; nt < 8; nt++) { gv[nt] = lg[nt * 16 + l16]; bv[nt] = lb[nt * 16 + l16]; }
    #pragma unroll
    for (int mt = 0; mt < 2; mt++)
        #pragma unroll
        for (int r = 0; r < 4; r++) {
            float s1 = 0.f, s2 = 0.f;
            #pragma unroll
            for (int nt = 0; nt < 8; nt++) { float v = acc2[mt][nt][r]; s1 += v; s2 += v * v; }
            #pragma unroll
            for (int m = 1; m < 16; m <<= 1) { s1 += __shfl_xor(s1, m, 64); s2 += __shfl_xor(s2, m, 64); }
            float mean = s1 * (1.f / 128.f);
            float sc = rsqrtf(s2 * (1.f / 128.f) - mean * mean + GN_EPS);
            int row = r0 + mt * 16 + quad * 4 + r;
            #pragma unroll
            for (int nt = 0; nt < 8; nt++) {
                float y = (acc2[mt][nt][r] - mean) * sc * gv[nt] + bv[nt];  // act=False before residual
                size_t o = (size_t)row * DD + nt * 16 + l16;
                outp[o] = fmaxf(y + resid[o], 0.f);
            }
        }
}

extern "C" void kernel_launch(void* const* d_in, const int* in_sizes, int n_in,
                              void* d_out, int out_size, void* d_ws, size_t ws_size,
                              hipStream_t stream)
{
    const float* actors     = (const float*)d_in[0];
    const float* nodes      = (const float*)d_in[1];
    const float* actor_ctrs = (const float*)d_in[2];
    const float* node_ctrs  = (const float*)d_in[3];
    const int*   hi         = (const int*)d_in[4];
    const int*   wi         = (const int*)d_in[5];
    const float* dist0_W    = (const float*)d_in[6];
    const float* dist0_b    = (const float*)d_in[7];
    const float* dist1_W    = (const float*)d_in[8];
    const float* dist1_g    = (const float*)d_in[9];
    const float* dist1_b    = (const float*)d_in[10];
    const float* query_W    = (const float*)d_in[11];
    const float* query_g    = (const float*)d_in[12];
    const float* query_b    = (const float*)d_in[13];
    const float* ctx0_W     = (const float*)d_in[14];
    const float* ctx0_g     = (const float*)d_in[15];
    const float* ctx0_b     = (const float*)d_in[16];
    const float* ctx1_W     = (const float*)d_in[17];
    const float* agt_W      = (const float*)d_in[18];
    const float* norm_g     = (const float*)d_in[19];
    const float* norm_b     = (const float*)d_in[20];
    const float* lin_W      = (const float*)d_in[21];
    const float* lin_g      = (const float*)d_in[22];
    const float* lin_b      = (const float*)d_in[23];

    // workspace layout (~34.6 MB)
    char* ws = (char*)d_ws;
    size_t off = 0;
    bf16*  Wf         = (bf16*)(ws + off);  off += 524288;      // 16 slices x 32 KB, fragment order
    float* A_acc      = (float*)(ws + off); off += 4194304;     // agt output, fragment-order f32
    float* M_acc      = (float*)(ws + off); off += 4194304;     // per-actor sum of m, ch-order f32
    float* actors_mid = (float*)(ws + off); off += 4194304;     // 4 MB
    bf16*  qc_bf      = (bf16*)(ws + off);  off += 2097152;     // 2 MB
    bf16*  nc_bf      = (bf16*)(ws + off);  off += 16777216;    // 16 MB
    int*   cnt        = (int*)(ws + off);   off += 32768;       // 8192 ints
    int*   cur        = (int*)(ws + off);   off += 32768;       // 8192 ints
    int*   hi_s       = (int*)(ws + off);   off += 1048576;     // E ints
    int*   wi_s       = (int*)(ws + off);   off += 1048576;     // E ints
    float2* dxy_s     = (float2*)(ws + off); off += 2097152;    // E float2

    repack_w_kernel<<<128, 256, 0, stream>>>(dist1_W, query_W, ctx0_W, ctx1_W, agt_W, lin_W,
                                             Wf, cnt);

    // counting sort by hi (shared by both Att blocks)
    hist_kernel<<<NEG / 256, 256, 0, stream>>>(hi, cnt);
    scan_kernel<<<1, 1024, 0, stream>>>(cnt, cur);
    scatter_kernel<<<NEG / 256, 256, 0, stream>>>(hi, wi, actor_ctrs, node_ctrs,
                                                  cur, hi_s, wi_s, dxy_s);

    for (int i = 0; i < 2; i++) {
        const bf16* d1f  = Wf + (size_t)(i * 8 + 0) * 16384;
        const bf16* qwf  = Wf + (size_t)(i * 8 + 1) * 16384;
        const bf16* c0df = Wf + (size_t)(i * 8 + 2) * 16384;
        const bf16* c0qf = Wf + (size_t)(i * 8 + 3) * 16384;
        const bf16* c0cf = Wf + (size_t)(i * 8 + 4) * 16384;
        const bf16* c1f  = Wf + (size_t)(i * 8 + 5) * 16384;
        const bf16* agf  = Wf + (size_t)(i * 8 + 6) * 16384;
        const bf16* lif  = Wf + (size_t)(i * 8 + 7) * 16384;
        const float* curp = i ? actors_mid : actors;
        float* nxt = i ? (float*)d_out : actors_mid;

        nodecprep_kernel<<<576, 256, 0, stream>>>(nodes, c0cf, nc_bf,
            curp, agf, qwf, query_g + i * 128, query_b + i * 128, c0qf,
            qc_bf, A_acc, M_acc);
        edge_kernel<<<NEG / 128, 256, 0, stream>>>(hi_s, wi_s, dxy_s,
            dist0_W + i * 256, dist0_b + i * 128,
            d1f, dist1_g + i * 128, dist1_b + i * 128,
            qc_bf, nc_bf, c0df, ctx0_g + i * 128, ctx0_b + i * 128, M_acc);
        post_kernel<<<NAC / 32, 64, 0, stream>>>(A_acc, M_acc, c1f,
            norm_g + i * 128, norm_b + i * 128,
            lif, lin_g + i * 128, lin_b + i * 128, curp, nxt);
    }
}